// Round 9
// baseline (236.385 us; speedup 1.0000x reference)
//
#include <hip/hip_runtime.h>

// Problem: B=4,S=4096,D=1024,H=16,HID=ATT=64
//   qkv = x @ [Wq|Wk|Wv] + bias       (16384 x 1024) @ (1024 x 3072)
//   per token: scores(16x16) = q k^T / 8 over HID=64; softmax over heads; ctx = P V
// R9: GEMM dataflow change: A direct global->VGPR (wave-private, reg double-buffer,
//     one slice ahead), B-only LDS (ring-4 x 16KB = 64KB, fragment-order, conflict-
//     free). Wave grid 4M x 2N so B is the shared operand (2x LDS reuse) and A rows
//     are private. Per-CU/slice walls: MFMA 1033 cyc (binding), LDS ~950, L2 ~860 —
//     removes the 96KB/slice LDS-read wall that capped R2-R8 at ~34% MfmaUtil.

#define AS1 __attribute__((address_space(1)))
#define AS3 __attribute__((address_space(3)))

typedef __bf16 bf16x8 __attribute__((ext_vector_type(8)));
typedef float f32x4 __attribute__((ext_vector_type(4)));
typedef float f32x16 __attribute__((ext_vector_type(16)));
typedef unsigned short u16x8 __attribute__((ext_vector_type(8)));

static constexpr int MTOK = 16384;   // B*S tokens
static constexpr int N3   = 3072;    // 3*H*HID
static constexpr int KD   = 1024;    // D

__device__ __forceinline__ unsigned short f2bf(float f) {
  unsigned u = __float_as_uint(f);
  unsigned r = u + 0x7FFFu + ((u >> 16) & 1u);   // round-to-nearest-even
  return (unsigned short)(r >> 16);
}
__device__ __forceinline__ float bf2f(unsigned short s) {
  return __uint_as_float(((unsigned)s) << 16);
}

__device__ __forceinline__ void gload_lds16(const void* g, void* lds_ptr) {
  __builtin_amdgcn_global_load_lds((const AS1 void*)g, (AS3 void*)lds_ptr, 16, 0, 0);
}

// ---------------- kernel 1: x f32 -> bf16 ----------------
__global__ __launch_bounds__(256) void cvt_x_kernel(const float* __restrict__ x,
                                                    unsigned short* __restrict__ xb) {
  int i = blockIdx.x * 256 + threadIdx.x;      // 8 elements per thread, exact grid
  const float4* p = (const float4*)x;
  float4 a = p[2 * i], b = p[2 * i + 1];
  u16x8 o;
  o[0] = f2bf(a.x); o[1] = f2bf(a.y); o[2] = f2bf(a.z); o[3] = f2bf(a.w);
  o[4] = f2bf(b.x); o[5] = f2bf(b.y); o[6] = f2bf(b.z); o[7] = f2bf(b.w);
  *((u16x8*)xb + i) = o;
}

// ------- kernel 2: W (K x N, f32) -> WT (N x K, bf16), bias concat -------
__global__ __launch_bounds__(256) void prep_w_kernel(const float* __restrict__ Wq,
                                                     const float* __restrict__ Wk,
                                                     const float* __restrict__ Wv,
                                                     const float* __restrict__ bq,
                                                     const float* __restrict__ bk,
                                                     const float* __restrict__ bv,
                                                     unsigned short* __restrict__ WT,
                                                     float* __restrict__ bcat) {
  __shared__ float tile[32][33];
  int kt = blockIdx.x * 32;          // k tile (0..1023)
  int nt = blockIdx.y * 32;          // global n tile (0..3071)
  const float* W; const float* bias; int nb;
  if (nt < 1024)      { W = Wq; bias = bq; nb = nt; }
  else if (nt < 2048) { W = Wk; bias = bk; nb = nt - 1024; }
  else                { W = Wv; bias = bv; nb = nt - 2048; }
  int tx = threadIdx.x & 31, ty = threadIdx.x >> 5;  // ty 0..7
#pragma unroll
  for (int it = 0; it < 4; ++it) {
    int kk = it * 8 + ty;
    tile[kk][tx] = W[(size_t)(kt + kk) * 1024 + nb + tx];
  }
  __syncthreads();
#pragma unroll
  for (int it = 0; it < 4; ++it) {
    int nn = it * 8 + ty;
    WT[(size_t)(nt + nn) * 1024 + kt + tx] = f2bf(tile[tx][nn]);
  }
  if (blockIdx.x == 0 && threadIdx.x < 32)
    bcat[nt + threadIdx.x] = bias[nb + threadIdx.x];
}

// ---------------- kernel 3: GEMM qkv = xb @ WT^T + bias (bf16 out) ----------------
// 256x256 tile, 512 threads = 8 waves (4M x 2N), per-wave C = 64x128 via 2x4 frags
// of v_mfma_f32_32x32x16_bf16. K = 32 slices of 32.
// A: DIRECT global->VGPR. Chunk (m,ks): lane l loads 16B at row m0+wm*64+m*32+(l&31),
//    k sl*32+ks*16+(l>>5)*8 — two ks-chunks cover each row's 64B line (full sectors).
//    Double-buffered in regs (aP/aQ), issued one slice ahead; compiler tracks waits.
// B: LDS ring of 4 slots x 16KB (fragment-order: frag fb=nb*2+ks at fb*512 elems,
//    chunk = lane*16B -> contiguous 1KB ds_read_b128, conflict-free by construction).
//    Staging: wave w writes fb=w and fb=w+8 (2 gload_lds16/thread/slice, linear dest).
// vmcnt ledger (per body issues: 4 A-loads then 2 B-gloads):
//    B(s) has >=12 VM ops after it at gate(s) (bodies s-2,s-1) -> vmcnt(8) forces
//    B(s) complete. Gates: prologue 4; 1..29: 8; 30: 6; 31: 4. A correctness is
//    compiler-tracked (ordinary loads, fenced by the asm volatile SYNCs).
// WAR: stage(s+3) -> slot (s-1)&3 issues after gate(s) barrier; slot (s-1)&3's
//    reads completed before their consuming MFMAs issued, which precede the barrier.
__global__ __launch_bounds__(512, 2) void gemm_qkv_kernel(const unsigned short* __restrict__ A,
                                                          const unsigned short* __restrict__ Bt,
                                                          const float* __restrict__ bias,
                                                          unsigned short* __restrict__ C) {
  __shared__ __align__(16) unsigned short lds[32768];  // 4 slots x 16 KB = 64 KiB
  const int tid  = threadIdx.x;
  const int lane = tid & 63;
  const int wave = tid >> 6;
  const int wm = wave >> 1, wn = wave & 1;   // 4M x 2N wave grid, per-wave 64x128
  const int m0 = blockIdx.x * 256;
  const int n0 = blockIdx.y * 256;

  // A per-thread base: chunk (m,ks) at slice sl = Ap + m*32*KD + sl*32 + ks*16
  const unsigned short* Ap = A + (size_t)(m0 + wm * 64 + (lane & 31)) * KD + ((lane >> 5) * 8);

  // B staging source (fragment fb=wave and fb=wave+8)
  const size_t bsrc0 = (size_t)(n0 + (wave >> 1) * 32 + (lane & 31)) * KD
                       + (wave & 1) * 16 + ((lane >> 5) * 8);
  const size_t bsrc1 = bsrc0 + (size_t)128 * KD;

  // B fragment ds_read offsets (elements within a slot)
  int boff[4][2];
#pragma unroll
  for (int n = 0; n < 4; ++n)
#pragma unroll
    for (int ks = 0; ks < 2; ++ks)
      boff[n][ks] = ((wn * 4 + n) * 2 + ks) * 512 + lane * 8;

  f32x16 acc[2][4] = {};
  bf16x8 aP[2][2], aQ[2][2];   // A reg double-buffer: [m][ks]

#define STAGE_B(SLOT, KK)                                                      \
  do {                                                                         \
    unsigned short* d0 = lds + (SLOT) * 8192 + tid * 8;                        \
    gload_lds16(Bt + bsrc0 + (KK), d0);                                        \
    gload_lds16(Bt + bsrc1 + (KK), d0 + 4096);                                 \
  } while (0)

#define LOAD_A(DST, KK)                                                        \
  do {                                                                         \
    _Pragma("unroll") for (int m = 0; m < 2; ++m)                              \
      _Pragma("unroll") for (int ks = 0; ks < 2; ++ks)                         \
        DST[m][ks] = *(const bf16x8*)(Ap + (size_t)m * 32 * KD + (KK) + ks * 16);\
  } while (0)

#define BODY(SLOT, AC, AN, KSL, DOSTAGE, DOLOADA)                              \
  do {                                                                         \
    const unsigned short* bufp = lds + (SLOT) * 8192;                          \
    bf16x8 bfr[4][2];                                                          \
    _Pragma("unroll") for (int n = 0; n < 4; ++n)                              \
      _Pragma("unroll") for (int ks = 0; ks < 2; ++ks)                         \
        bfr[n][ks] = *(const bf16x8*)(bufp + boff[n][ks]);                     \
    if (DOLOADA) { LOAD_A(AN, (KSL) + 32); }                                   \
    if (DOSTAGE) { STAGE_B(((SLOT) + 3) & 3, (KSL) + 96); }                    \
    __builtin_amdgcn_sched_barrier(0);                                         \
    __builtin_amdgcn_s_setprio(1);                                             \
    _Pragma("unroll") for (int ks = 0; ks < 2; ++ks)                           \
      _Pragma("unroll") for (int m = 0; m < 2; ++m)                            \
        _Pragma("unroll") for (int n = 0; n < 4; ++n)                          \
          acc[m][n] = __builtin_amdgcn_mfma_f32_32x32x16_bf16(AC[m][ks],       \
                          bfr[n][ks], acc[m][n], 0, 0, 0);                     \
    __builtin_amdgcn_s_setprio(0);                                             \
  } while (0)

#define SYNC(VM)                                                               \
  do {                                                                         \
    asm volatile("s_waitcnt vmcnt(" #VM ")" ::: "memory");                     \
    __builtin_amdgcn_s_barrier();                                              \
  } while (0)

  // prologue: A(0) -> aP; stage B slices 0,1,2 into slots 0,1,2
  LOAD_A(aP, 0);
  STAGE_B(0, 0); STAGE_B(1, 32); STAGE_B(2, 64);
  SYNC(4);   // drains A(0) (compiler also tracks) and B(0); leaves B(1),B(2)

  // main: slices 0..27 (body s: consume A(s)/B(s), load A(s+1), stage B(s+3))
#pragma unroll 1
  for (int t = 0; t < 7; ++t) {
    const int kb = t * 128;
    BODY(0, aP, aQ, kb,       true, true); SYNC(8);
    BODY(1, aQ, aP, kb + 32,  true, true); SYNC(8);
    BODY(2, aP, aQ, kb + 64,  true, true); SYNC(8);
    BODY(3, aQ, aP, kb + 96,  true, true); SYNC(8);
  }
  // tail: s=28 (stage B31, load A29), 29 (load A30), 30 (load A31), 31
  BODY(0, aP, aQ, 896, true,  true);  SYNC(8);
  BODY(1, aQ, aP, 928, false, true);  SYNC(6);
  BODY(2, aP, aQ, 960, false, true);  SYNC(4);
  BODY(3, aQ, aP, 992, false, false);
#undef STAGE_B
#undef LOAD_A
#undef BODY
#undef SYNC

  // epilogue: 32x32 C/D layout: col = lane&31, row = (r&3) + 8*(r>>2) + 4*(lane>>5)
  // -> each store: 32 lanes x 2B = 64B full sector.
#pragma unroll
  for (int n = 0; n < 4; ++n) {
    int col = n0 + wn * 128 + n * 32 + (lane & 31);
    float bvv = bias[col];
#pragma unroll
    for (int m = 0; m < 2; ++m) {
      int rowb = m0 + wm * 64 + m * 32 + 4 * (lane >> 5);
#pragma unroll
      for (int r = 0; r < 16; ++r) {
        int row = rowb + (r & 3) + 8 * (r >> 2);
        C[(size_t)row * N3 + col] = f2bf(acc[m][n][r] + bvv);
      }
    }
  }
}

// ---------------- kernel 4: per-token head attention ----------------
// 1 wave per token; scores via 2 MFMAs straight from global; softmax across 16-lane
// groups; P -> LDS; PV on VALU; coalesced f32 out.
__global__ __launch_bounds__(256) void attn_kernel(const unsigned short* __restrict__ qkv,
                                                   float* __restrict__ out) {
  __shared__ float p_lds[4][16][17];
  const int tid = threadIdx.x;
  const int lane = tid & 63;
  const int w = tid >> 6;
  const size_t token = (size_t)blockIdx.x * 4 + w;
  const unsigned short* rowp = qkv + token * N3;
  const int head = lane & 15;     // A-frag row (q head) and B-frag col (k head)
  const int chunk = lane >> 4;    // k-dim subchunk

  const int o = head * 64 + chunk * 8;
  bf16x8 q0 = *(const bf16x8*)(rowp + o);
  bf16x8 q1 = *(const bf16x8*)(rowp + o + 32);
  bf16x8 k0 = *(const bf16x8*)(rowp + 1024 + o);
  bf16x8 k1 = *(const bf16x8*)(rowp + 1024 + o + 32);
  f32x4 c = {0.f, 0.f, 0.f, 0.f};
  c = __builtin_amdgcn_mfma_f32_16x16x32_bf16(q0, k0, c, 0, 0, 0);
  c = __builtin_amdgcn_mfma_f32_16x16x32_bf16(q1, k1, c, 0, 0, 0);
  // c[r] = scores[row = chunk*4+r][col = head]

#pragma unroll
  for (int r = 0; r < 4; ++r) {
    float s = c[r] * 0.125f;
    float m = s;
#pragma unroll
    for (int off = 1; off < 16; off <<= 1) m = fmaxf(m, __shfl_xor(m, off, 64));
    float e = __expf(s - m);
    float sum = e;
#pragma unroll
    for (int off = 1; off < 16; off <<= 1) sum += __shfl_xor(sum, off, 64);
    p_lds[w][chunk * 4 + r][head] = e / sum;
  }
  __syncthreads();

  // PV: lane owns (i = lane>>2, a-block = lane&3): 16 f32 outputs
  const int i = lane >> 2;
  const int ab = lane & 3;
  const unsigned short* vbase = rowp + 2048 + ab * 16;
  float accv[16];
#pragma unroll
  for (int cc = 0; cc < 16; ++cc) accv[cc] = 0.f;
#pragma unroll
  for (int j = 0; j < 16; ++j) {
    float pij = p_lds[w][i][j];
    u16x8 v0 = *(const u16x8*)(vbase + j * 64);
    u16x8 v1 = *(const u16x8*)(vbase + j * 64 + 8);
#pragma unroll
    for (int cc = 0; cc < 8; ++cc) accv[cc] += pij * bf2f(v0[cc]);
#pragma unroll
    for (int cc = 0; cc < 8; ++cc) accv[8 + cc] += pij * bf2f(v1[cc]);
  }
  float* op = out + token * 1024 + i * 64 + ab * 16;
#pragma unroll
  for (int cc = 0; cc < 16; cc += 4) {
    f32x4 v = {accv[cc], accv[cc + 1], accv[cc + 2], accv[cc + 3]};
    *(f32x4*)(op + cc) = v;
  }
}

extern "C" void kernel_launch(void* const* d_in, const int* in_sizes, int n_in,
                              void* d_out, int out_size, void* d_ws, size_t ws_size,
                              hipStream_t stream) {
  const float* x  = (const float*)d_in[0];
  const float* Wq = (const float*)d_in[1];
  const float* bq = (const float*)d_in[2];
  const float* Wk = (const float*)d_in[3];
  const float* bk = (const float*)d_in[4];
  const float* Wv = (const float*)d_in[5];
  const float* bv = (const float*)d_in[6];
  float* out = (float*)d_out;

  char* ws = (char*)d_ws;
  unsigned short* xb   = (unsigned short*)ws;               // 16384*1024*2 = 33,554,432
  unsigned short* WT   = (unsigned short*)(ws + 33554432);  //  3072*1024*2 =  6,291,456
  float*          bcat = (float*)(ws + 39845888);           //  3072*4      =     12,288
  unsigned short* qkv  = (unsigned short*)(ws + 39858176);  // 16384*3072*2 = 100,663,296

  cvt_x_kernel<<<dim3((MTOK * KD / 8) / 256), 256, 0, stream>>>(x, xb);
  prep_w_kernel<<<dim3(32, 96), 256, 0, stream>>>(Wq, Wk, Wv, bq, bk, bv, WT, bcat);
  gemm_qkv_kernel<<<dim3(MTOK / 256, N3 / 256), 512, 0, stream>>>(xb, WT, bcat, qkv);
  attn_kernel<<<dim3(MTOK / 4), 256, 0, stream>>>(qkv, out);
}

// Round 10
// 178.553 us; speedup vs baseline: 1.3239x; 1.3239x over previous
//
#include <hip/hip_runtime.h>

// Problem: B=4,S=4096,D=1024,H=16,HID=ATT=64
//   qkv = x @ [Wq|Wk|Wv] + bias       (16384 x 1024) @ (1024 x 3072)
//   per token: scores(16x16) = q k^T / 8 over HID=64; softmax over heads; ctx = P V
// R10: occupancy experiment. R4's exact fragment geometry + phase content, but LDS
//      halved to 64 KiB (ring-2 x 32KB BK=32 slots) so 2 blocks/CU co-reside and
//      fill each other's barrier stalls (m114 mechanism: cross-block overlap is
//      what the m97-class structure actually uses). Stage 1 slice ahead, vmcnt(0)
//      + barrier per slice.

#define AS1 __attribute__((address_space(1)))
#define AS3 __attribute__((address_space(3)))

typedef __bf16 bf16x8 __attribute__((ext_vector_type(8)));
typedef float f32x4 __attribute__((ext_vector_type(4)));
typedef float f32x16 __attribute__((ext_vector_type(16)));
typedef unsigned short u16x8 __attribute__((ext_vector_type(8)));

static constexpr int MTOK = 16384;   // B*S tokens
static constexpr int N3   = 3072;    // 3*H*HID
static constexpr int KD   = 1024;    // D

__device__ __forceinline__ unsigned short f2bf(float f) {
  unsigned u = __float_as_uint(f);
  unsigned r = u + 0x7FFFu + ((u >> 16) & 1u);   // round-to-nearest-even
  return (unsigned short)(r >> 16);
}
__device__ __forceinline__ float bf2f(unsigned short s) {
  return __uint_as_float(((unsigned)s) << 16);
}

__device__ __forceinline__ void gload_lds16(const void* g, void* lds_ptr) {
  __builtin_amdgcn_global_load_lds((const AS1 void*)g, (AS3 void*)lds_ptr, 16, 0, 0);
}

// ---------------- kernel 1: x f32 -> bf16 ----------------
__global__ __launch_bounds__(256) void cvt_x_kernel(const float* __restrict__ x,
                                                    unsigned short* __restrict__ xb) {
  int i = blockIdx.x * 256 + threadIdx.x;      // 8 elements per thread, exact grid
  const float4* p = (const float4*)x;
  float4 a = p[2 * i], b = p[2 * i + 1];
  u16x8 o;
  o[0] = f2bf(a.x); o[1] = f2bf(a.y); o[2] = f2bf(a.z); o[3] = f2bf(a.w);
  o[4] = f2bf(b.x); o[5] = f2bf(b.y); o[6] = f2bf(b.z); o[7] = f2bf(b.w);
  *((u16x8*)xb + i) = o;
}

// ------- kernel 2: W (K x N, f32) -> WT (N x K, bf16), bias concat -------
__global__ __launch_bounds__(256) void prep_w_kernel(const float* __restrict__ Wq,
                                                     const float* __restrict__ Wk,
                                                     const float* __restrict__ Wv,
                                                     const float* __restrict__ bq,
                                                     const float* __restrict__ bk,
                                                     const float* __restrict__ bv,
                                                     unsigned short* __restrict__ WT,
                                                     float* __restrict__ bcat) {
  __shared__ float tile[32][33];
  int kt = blockIdx.x * 32;          // k tile (0..1023)
  int nt = blockIdx.y * 32;          // global n tile (0..3071)
  const float* W; const float* bias; int nb;
  if (nt < 1024)      { W = Wq; bias = bq; nb = nt; }
  else if (nt < 2048) { W = Wk; bias = bk; nb = nt - 1024; }
  else                { W = Wv; bias = bv; nb = nt - 2048; }
  int tx = threadIdx.x & 31, ty = threadIdx.x >> 5;  // ty 0..7
#pragma unroll
  for (int it = 0; it < 4; ++it) {
    int kk = it * 8 + ty;
    tile[kk][tx] = W[(size_t)(kt + kk) * 1024 + nb + tx];
  }
  __syncthreads();
#pragma unroll
  for (int it = 0; it < 4; ++it) {
    int nn = it * 8 + ty;
    WT[(size_t)(nt + nn) * 1024 + kt + tx] = f2bf(tile[tx][nn]);
  }
  if (blockIdx.x == 0 && threadIdx.x < 32)
    bcat[nt + threadIdx.x] = bias[nb + threadIdx.x];
}

// ---------------- kernel 3: GEMM qkv = xb @ WT^T + bias (bf16 out) ----------------
// 256x256 tile, 512 threads = 8 waves (2M x 4N), per-wave C = 128x64 via 4x2 frags
// of v_mfma_f32_32x32x16_bf16. K = 32 slices of 32.
// LDS: ring-2 x 32KB slot (slot = slice&1) = 64 KiB -> 2 blocks/CU co-resident.
//   Slot: A[256 rows][32 k] | B at +8192 elems; 16B chunk c of row r at element
//   r*32 + (c ^ ((r>>1)&3))*8 (R4 layout). gload_lds dest LINEAR; global SOURCE
//   pre-permuted with the same involution (rule #21).
// Body s: reads(12 b128, slot s&1); STAGE(s+1 -> slot (s+1)&1); setprio; 16 MFMA;
//   setprio; then SYNC{vmcnt(0); barrier}.
// WAR: slot (s+1)&1 holds slice s-1, whose reads were consumed (operand-ready)
//   before each wave issued its body-(s-1) MFMAs, hence before the barrier ending
//   body s-1 -> staging in body s is safe. RAW: vmcnt(0) at SYNC drains the 4
//   stage-loads of s+1 (the only outstanding VM ops) before body s+1 reads them;
//   ~full-body latency (>=1000 cyc) covers L2/HBM.
__global__ __launch_bounds__(512, 2) void gemm_qkv_kernel(const unsigned short* __restrict__ A,
                                                          const unsigned short* __restrict__ Bt,
                                                          const float* __restrict__ bias,
                                                          unsigned short* __restrict__ C) {
  __shared__ __align__(16) unsigned short lds[32768];  // 2 slots x 32 KB = 64 KiB
  const int tid  = threadIdx.x;
  const int lane = tid & 63;
  const int wave = tid >> 6;
  const int wm = wave >> 2, wn = wave & 3;   // 2x4 wave grid, per-wave 128x64
  const int m0 = blockIdx.x * 256;
  const int n0 = blockIdx.y * 256;

  // staging decode: thread owns linear 16B chunk j=tid of each 4KB quarter.
  // chunk j: row=j>>2, phys slot j&3, logical c=(j&3)^((row>>1)&3).
  const int srow = tid >> 2;                               // 0..127
  const int sc   = ((tid & 3) ^ ((srow >> 1) & 3)) * 8;    // logical k-offset (elems)
  const size_t asrc0 = (size_t)(m0 + srow) * KD + sc;
  const size_t asrc1 = (size_t)(m0 + 128 + srow) * KD + sc;  // (r+128): same swizzle bits
  const size_t bsrc0 = (size_t)(n0 + srow) * KD + sc;
  const size_t bsrc1 = (size_t)(n0 + 128 + srow) * KD + sc;

  // fragment ds_read offsets (elements within a slot); ks = k-substep (16-k) 0/1
  int aoff[4][2], boff[2][2];
#pragma unroll
  for (int m = 0; m < 4; ++m) {
    int row = wm * 128 + m * 32 + (lane & 31);
#pragma unroll
    for (int ks = 0; ks < 2; ++ks) {
      int pc = (ks * 2 + (lane >> 5)) ^ ((row >> 1) & 3);
      aoff[m][ks] = row * 32 + pc * 8;
    }
  }
#pragma unroll
  for (int n = 0; n < 2; ++n) {
    int row = wn * 64 + n * 32 + (lane & 31);
#pragma unroll
    for (int ks = 0; ks < 2; ++ks) {
      int pc = (ks * 2 + (lane >> 5)) ^ ((row >> 1) & 3);
      boff[n][ks] = 8192 + row * 32 + pc * 8;
    }
  }

  f32x16 acc[4][2] = {};

#define STAGE(SLOT, KK)                                                        \
  do {                                                                         \
    unsigned short* dst = lds + (SLOT) * 16384 + tid * 8;                      \
    gload_lds16(A  + asrc0 + (KK), dst);                                       \
    gload_lds16(A  + asrc1 + (KK), dst + 4096);                                \
    gload_lds16(Bt + bsrc0 + (KK), dst + 8192);                                \
    gload_lds16(Bt + bsrc1 + (KK), dst + 12288);                               \
  } while (0)

  // prologue: stage slice 0 into slot 0; wait it in
  STAGE(0, 0);
  asm volatile("s_waitcnt vmcnt(0)" ::: "memory");
  __builtin_amdgcn_s_barrier();

#pragma unroll 1
  for (int s = 0; s < 32; ++s) {
    const unsigned short* bufp = lds + (s & 1) * 16384;
    bf16x8 af[4][2], bfr[2][2];
#pragma unroll
    for (int m = 0; m < 4; ++m)
#pragma unroll
      for (int ks = 0; ks < 2; ++ks)
        af[m][ks] = *(const bf16x8*)(bufp + aoff[m][ks]);
#pragma unroll
    for (int n = 0; n < 2; ++n)
#pragma unroll
      for (int ks = 0; ks < 2; ++ks)
        bfr[n][ks] = *(const bf16x8*)(bufp + boff[n][ks]);
    if (s < 31) {
      unsigned short* dst = lds + ((s + 1) & 1) * 16384 + tid * 8;
      const int kk = (s + 1) * 32;
      gload_lds16(A  + asrc0 + kk, dst);
      gload_lds16(A  + asrc1 + kk, dst + 4096);
      gload_lds16(Bt + bsrc0 + kk, dst + 8192);
      gload_lds16(Bt + bsrc1 + kk, dst + 12288);
    }
    __builtin_amdgcn_s_setprio(1);
#pragma unroll
    for (int ks = 0; ks < 2; ++ks)
#pragma unroll
      for (int m = 0; m < 4; ++m)
#pragma unroll
        for (int n = 0; n < 2; ++n)
          acc[m][n] = __builtin_amdgcn_mfma_f32_32x32x16_bf16(af[m][ks], bfr[n][ks],
                                                              acc[m][n], 0, 0, 0);
    __builtin_amdgcn_s_setprio(0);
    if (s < 31) {
      asm volatile("s_waitcnt vmcnt(0)" ::: "memory");
      __builtin_amdgcn_s_barrier();
    }
  }
#undef STAGE

  // epilogue: 32x32 C/D layout: col = lane&31, row = (r&3) + 8*(r>>2) + 4*(lane>>5)
  // -> each store: 32 lanes x 2B = 64B full sector.
#pragma unroll
  for (int n = 0; n < 2; ++n) {
    int col = n0 + wn * 64 + n * 32 + (lane & 31);
    float bvv = bias[col];
#pragma unroll
    for (int m = 0; m < 4; ++m) {
      int rowb = m0 + wm * 128 + m * 32 + 4 * (lane >> 5);
#pragma unroll
      for (int r = 0; r < 16; ++r) {
        int row = rowb + (r & 3) + 8 * (r >> 2);
        C[(size_t)row * N3 + col] = f2bf(acc[m][n][r] + bvv);
      }
    }
  }
}

// ---------------- kernel 4: per-token head attention ----------------
// 1 wave per token; scores via 2 MFMAs straight from global; softmax across 16-lane
// groups; P -> LDS; PV on VALU; coalesced f32 out.
__global__ __launch_bounds__(256) void attn_kernel(const unsigned short* __restrict__ qkv,
                                                   float* __restrict__ out) {
  __shared__ float p_lds[4][16][17];
  const int tid = threadIdx.x;
  const int lane = tid & 63;
  const int w = tid >> 6;
  const size_t token = (size_t)blockIdx.x * 4 + w;
  const unsigned short* rowp = qkv + token * N3;
  const int head = lane & 15;     // A-frag row (q head) and B-frag col (k head)
  const int chunk = lane >> 4;    // k-dim subchunk

  const int o = head * 64 + chunk * 8;
  bf16x8 q0 = *(const bf16x8*)(rowp + o);
  bf16x8 q1 = *(const bf16x8*)(rowp + o + 32);
  bf16x8 k0 = *(const bf16x8*)(rowp + 1024 + o);
  bf16x8 k1 = *(const bf16x8*)(rowp + 1024 + o + 32);
  f32x4 c = {0.f, 0.f, 0.f, 0.f};
  c = __builtin_amdgcn_mfma_f32_16x16x32_bf16(q0, k0, c, 0, 0, 0);
  c = __builtin_amdgcn_mfma_f32_16x16x32_bf16(q1, k1, c, 0, 0, 0);
  // c[r] = scores[row = chunk*4+r][col = head]

#pragma unroll
  for (int r = 0; r < 4; ++r) {
    float s = c[r] * 0.125f;
    float m = s;
#pragma unroll
    for (int off = 1; off < 16; off <<= 1) m = fmaxf(m, __shfl_xor(m, off, 64));
    float e = __expf(s - m);
    float sum = e;
#pragma unroll
    for (int off = 1; off < 16; off <<= 1) sum += __shfl_xor(sum, off, 64);
    p_lds[w][chunk * 4 + r][head] = e / sum;
  }
  __syncthreads();

  // PV: lane owns (i = lane>>2, a-block = lane&3): 16 f32 outputs
  const int i = lane >> 2;
  const int ab = lane & 3;
  const unsigned short* vbase = rowp + 2048 + ab * 16;
  float accv[16];
#pragma unroll
  for (int cc = 0; cc < 16; ++cc) accv[cc] = 0.f;
#pragma unroll
  for (int j = 0; j < 16; ++j) {
    float pij = p_lds[w][i][j];
    u16x8 v0 = *(const u16x8*)(vbase + j * 64);
    u16x8 v1 = *(const u16x8*)(vbase + j * 64 + 8);
#pragma unroll
    for (int cc = 0; cc < 8; ++cc) accv[cc] += pij * bf2f(v0[cc]);
#pragma unroll
    for (int cc = 0; cc < 8; ++cc) accv[8 + cc] += pij * bf2f(v1[cc]);
  }
  float* op = out + token * 1024 + i * 64 + ab * 16;
#pragma unroll
  for (int cc = 0; cc < 16; cc += 4) {
    f32x4 v = {accv[cc], accv[cc + 1], accv[cc + 2], accv[cc + 3]};
    *(f32x4*)(op + cc) = v;
  }
}

extern "C" void kernel_launch(void* const* d_in, const int* in_sizes, int n_in,
                              void* d_out, int out_size, void* d_ws, size_t ws_size,
                              hipStream_t stream) {
  const float* x  = (const float*)d_in[0];
  const float* Wq = (const float*)d_in[1];
  const float* bq = (const float*)d_in[2];
  const float* Wk = (const float*)d_in[3];
  const float* bk = (const float*)d_in[4];
  const float* Wv = (const float*)d_in[5];
  const float* bv = (const float*)d_in[6];
  float* out = (float*)d_out;

  char* ws = (char*)d_ws;
  unsigned short* xb   = (unsigned short*)ws;               // 16384*1024*2 = 33,554,432
  unsigned short* WT   = (unsigned short*)(ws + 33554432);  //  3072*1024*2 =  6,291,456
  float*          bcat = (float*)(ws + 39845888);           //  3072*4      =     12,288
  unsigned short* qkv  = (unsigned short*)(ws + 39858176);  // 16384*3072*2 = 100,663,296

  cvt_x_kernel<<<dim3((MTOK * KD / 8) / 256), 256, 0, stream>>>(x, xb);
  prep_w_kernel<<<dim3(32, 96), 256, 0, stream>>>(Wq, Wk, Wv, bq, bk, bv, WT, bcat);
  gemm_qkv_kernel<<<dim3(MTOK / 256, N3 / 256), 512, 0, stream>>>(xb, WT, bcat, qkv);
  attn_kernel<<<dim3(MTOK / 4), 256, 0, stream>>>(qkv, out);
}